// Round 8
// baseline (261.116 us; speedup 1.0000x reference)
//
#include <hip/hip_runtime.h>
#include <hip/hip_bf16.h>
#include <math.h>

// Problem constants
#define BB      4
#define NN      2048
#define DM      768
#define NH      8
#define DHH     96
#define BH      (BB*NH)          // 32
#define MROWS   (BB*NN)          // 8192
#define NC_QKV  (3*DM)           // 2304

typedef short v4s  __attribute__((ext_vector_type(4)));
typedef short v8s  __attribute__((ext_vector_type(8)));
typedef float v16f __attribute__((ext_vector_type(16)));
typedef unsigned int u32;

// log2(e)/sqrt(96) folded into Q at QKV-GEMM epilogue
#define SCQ 0.14724599350930152f

static __device__ __forceinline__ ushort f2bf(float f) {
    __hip_bfloat16 h = __float2bfloat16(f);
    return *reinterpret_cast<ushort*>(&h);
}
static __device__ __forceinline__ float bf2f(ushort u) {
    u32 x = ((u32)u) << 16;
    return __uint_as_float(x);
}

static __device__ __forceinline__ void gload_lds16(const ushort* g, ushort* l) {
    __builtin_amdgcn_global_load_lds(
        (const __attribute__((address_space(1))) void*)g,
        (__attribute__((address_space(3))) void*)l, 16, 0, 0);
}

// two 8B LDS loads 16B apart -> one v8s fragment (ds_read2_b64)
static __device__ __forceinline__ v8s load2x4(const ushort* p) {
    union { v4s h[2]; v8s s; } x;
    x.h[0] = *reinterpret_cast<const v4s*>(p);
    x.h[1] = *reinterpret_cast<const v4s*>(p + 8);
    return x.s;
}

static __device__ __forceinline__ v8s pack4(u32 a, u32 b, u32 c, u32 d) {
    union { u32 u[4]; v8s s; } x;
    x.u[0] = a; x.u[1] = b; x.u[2] = c; x.u[3] = d;
    return x.s;
}

// ---------------------------------------------------------------------------
// fp32 -> bf16 elementwise (n8 = count/8)
// ---------------------------------------------------------------------------
__global__ __launch_bounds__(256)
void conv_bf16(const float* __restrict__ in, ushort* __restrict__ out, int n8)
{
    int i = blockIdx.x * 256 + threadIdx.x;
    if (i >= n8) return;
    const float4* p = reinterpret_cast<const float4*>(in) + (size_t)i * 2;
    float4 a = p[0], b = p[1];
    ushort r[8] = {f2bf(a.x), f2bf(a.y), f2bf(a.z), f2bf(a.w),
                   f2bf(b.x), f2bf(b.y), f2bf(b.z), f2bf(b.w)};
    *reinterpret_cast<v8s*>(out + (size_t)i * 8) = *reinterpret_cast<v8s*>(r);
}

// ---------------------------------------------------------------------------
// fp32 W[K][N] -> bf16 Wt[N][K] (tiled transpose)
// ---------------------------------------------------------------------------
__global__ __launch_bounds__(256)
void convT_bf16(const float* __restrict__ W, ushort* __restrict__ Wt, int K, int N)
{
    __shared__ ushort t[32][33];
    const int k0 = blockIdx.x * 32, n0 = blockIdx.y * 32;
    const int tx = threadIdx.x & 31, ty = threadIdx.x >> 5;
    #pragma unroll
    for (int r = ty; r < 32; r += 8)
        t[tx][r] = f2bf(W[(size_t)(k0 + r) * N + n0 + tx]);
    __syncthreads();
    #pragma unroll
    for (int r = ty; r < 32; r += 8)
        Wt[(size_t)(n0 + r) * K + k0 + tx] = t[r][tx];
}

// ---------------------------------------------------------------------------
// bf16 MFMA GEMM (unchanged from rounds 6/7, harness-proven).
// ---------------------------------------------------------------------------
template<int SCATTER>
__global__ __launch_bounds__(256)
void gemm_mfma(const ushort* __restrict__ A, const ushort* __restrict__ Bt,
               const float* __restrict__ bias, void* __restrict__ outp,
               int K, int Ncols)
{
    __shared__ ushort As[2][8192];   // [buf][8 kslots][128 rows][8]
    __shared__ ushort Bs[2][8192];

    const int tid  = threadIdx.x;
    const int lane = tid & 63;
    const int wv   = tid >> 6;
    const int l31  = lane & 31;
    const int lhi  = lane >> 5;
    const int wr   = wv >> 1, wc = wv & 1;

    const int ny   = gridDim.y;
    const int id   = blockIdx.y * gridDim.x + blockIdx.x;
    const int c8   = id & 7;
    const int j    = id >> 3;
    const int hy   = (j >= (ny >> 1) * 8) ? 1 : 0;
    const int w    = j - hy * (ny >> 1) * 8;
    const int bx   = c8 * 8 + (w & 7);
    const int by   = hy * (ny >> 1) + (w >> 3);
    const int row0 = bx * 128;
    const int col0 = by * 128;

    v16f acc[2][2];
    #pragma unroll
    for (int mi = 0; mi < 2; ++mi)
        #pragma unroll
        for (int nj = 0; nj < 2; ++nj)
            #pragma unroll
            for (int i = 0; i < 16; ++i) acc[mi][nj][i] = 0.0f;

#define STAGE_G(bsel, kk) do {                                                  \
    _Pragma("unroll")                                                           \
    for (int c = 0; c < 4; ++c) {                                               \
        const int g   = c * 4 + wv;                                             \
        const int idx = g * 64 + lane;                                          \
        const int ss  = idx >> 7, rr = idx & 127;                               \
        gload_lds16(&A [(size_t)(row0 + rr) * K + (kk) + ss * 8],               \
                    &As[bsel][g * 512]);                                        \
        gload_lds16(&Bt[(size_t)(col0 + rr) * K + (kk) + ss * 8],               \
                    &Bs[bsel][g * 512]);                                        \
    }                                                                           \
} while (0)

    STAGE_G(0, 0);
    __syncthreads();

    const int nk = K >> 6;
    for (int t = 0; t < nk; ++t) {
        const int cur = t & 1;
        if (t + 1 < nk) STAGE_G(cur ^ 1, (t + 1) << 6);

        #pragma unroll
        for (int s16 = 0; s16 < 4; ++s16) {
            const int ks = s16 * 2 + lhi;
            v8s a0 = *reinterpret_cast<const v8s*>(&As[cur][(size_t)(ks * 128 + 64 * wr + l31) * 8]);
            v8s a1 = *reinterpret_cast<const v8s*>(&As[cur][(size_t)(ks * 128 + 64 * wr + 32 + l31) * 8]);
            v8s b0 = *reinterpret_cast<const v8s*>(&Bs[cur][(size_t)(ks * 128 + 64 * wc + l31) * 8]);
            v8s b1 = *reinterpret_cast<const v8s*>(&Bs[cur][(size_t)(ks * 128 + 64 * wc + 32 + l31) * 8]);
            acc[0][0] = __builtin_amdgcn_mfma_f32_32x32x16_bf16(a0, b0, acc[0][0], 0, 0, 0);
            acc[0][1] = __builtin_amdgcn_mfma_f32_32x32x16_bf16(a0, b1, acc[0][1], 0, 0, 0);
            acc[1][0] = __builtin_amdgcn_mfma_f32_32x32x16_bf16(a1, b0, acc[1][0], 0, 0, 0);
            acc[1][1] = __builtin_amdgcn_mfma_f32_32x32x16_bf16(a1, b1, acc[1][1], 0, 0, 0);
        }
        __syncthreads();
    }
#undef STAGE_G

    #pragma unroll
    for (int nj = 0; nj < 2; ++nj) {
        const int c = col0 + 64 * wc + 32 * nj + l31;
        const float bv = bias[c];
        #pragma unroll
        for (int mi = 0; mi < 2; ++mi) {
            #pragma unroll
            for (int r = 0; r < 16; ++r) {
                const int m = row0 + 64 * wr + 32 * mi + (r & 3) + 8 * (r >> 2) + 4 * lhi;
                float v = acc[mi][nj][r] + bv;
                if (SCATTER) {
                    const int s   = c / DM;
                    const int rem = c - s * DM;
                    const int h   = rem / DHH;
                    const int d   = rem - h * DHH;
                    const int b   = m >> 11;
                    const int n   = m & (NN - 1);
                    if (s == 0) v *= SCQ;
                    ((ushort*)outp)[((size_t)(s * BH + b * NH + h) * NN + n) * DHH + d] = f2bf(v);
                } else {
                    ((float*)outp)[(size_t)m * Ncols + c] = v;
                }
            }
        }
    }
}

// ---------------------------------------------------------------------------
// Split-KV MFMA bf16 flash attention. 512 threads = 8 waves x 32 q rows,
// grid (8 qt, 32 bh, 2 KV-halves) -> 512 blocks, 2/CU, 16 waves/CU (4/SIMD).
// Single-buffered K,V LDS (24.8 KB) with read->barrier->write->barrier
// handoff; staging split K:waves0-3 / V:waves4-7 (reg pressure <=128).
// No max-subtraction -> halves combine additively: raw bf16 O partial +
// f32 dsum per row; combine kernel normalizes.
// ---------------------------------------------------------------------------
__global__ __launch_bounds__(512, 4)
void attn_mfma(const ushort* __restrict__ qkv,
               ushort* __restrict__ O0, ushort* __restrict__ O1,
               float* __restrict__ dsw)
{
    __shared__ ushort Ks[6144];        // [kslot g=12][kv=64][8]
    __shared__ ushort Vt[96][68];      // [d][kv], pad 68 (2-way, free)

    const int tid  = threadIdx.x;
    const int lane = tid & 63;
    const int wv   = tid >> 6;          // 0..7
    const int w2   = wv & 3;
    const int l31  = lane & 31;
    const int lhi  = lane >> 5;

    // swizzle: XCD c8 gets a 4-bh cluster (KV L2-resident), all qt, both halves
    const int id   = blockIdx.z * (gridDim.x * gridDim.y)
                   + blockIdx.y * gridDim.x + blockIdx.x;   // 0..511
    const int c8   = id & 7;
    const int j    = id >> 3;            // 0..63
    const int bh   = c8 * 4 + (j & 3);
    const int qt   = (j >> 2) & 7;
    const int half = j >> 5;
    const int q0   = qt * 256;
    const int b    = bh >> 3, h = bh & 7;

    const ushort* Qg = qkv + (size_t)bh * NN * DHH;
    const ushort* Kg = qkv + ((size_t)BH + bh) * NN * DHH;
    const ushort* Vg = qkv + ((size_t)2 * BH + bh) * NN * DHH;

    // Q fragments (pre-scaled by SCQ): q row = q0 + wv*32 + l31
    const int qr = q0 + wv * 32 + l31;
    v8s qf[6];
    #pragma unroll
    for (int kt = 0; kt < 6; ++kt)
        qf[kt] = *reinterpret_cast<const v8s*>(&Qg[(size_t)qr * DHH + kt * 16 + lhi * 8]);

    v16f o[3];
    #pragma unroll
    for (int dt = 0; dt < 3; ++dt)
        #pragma unroll
        for (int i = 0; i < 16; ++i) o[dt][i] = 0.0f;
    float ds4[4] = {0.0f, 0.0f, 0.0f, 0.0f};

    const int ts = half * 16, te = ts + 16;

    // ---- prologue: stage tile ts (K: waves 0-3, V: waves 4-7)
    {
        const size_t rowb = (size_t)(ts * 64 + lane) * DHH;
        if (wv < 4) {
            v8s k0r = *reinterpret_cast<const v8s*>(&Kg[rowb + (w2 * 3 + 0) * 8]);
            v8s k1r = *reinterpret_cast<const v8s*>(&Kg[rowb + (w2 * 3 + 1) * 8]);
            v8s k2r = *reinterpret_cast<const v8s*>(&Kg[rowb + (w2 * 3 + 2) * 8]);
            *reinterpret_cast<v8s*>(&Ks[(w2 * 3 + 0) * 512 + lane * 8]) = k0r;
            *reinterpret_cast<v8s*>(&Ks[(w2 * 3 + 1) * 512 + lane * 8]) = k1r;
            *reinterpret_cast<v8s*>(&Ks[(w2 * 3 + 2) * 512 + lane * 8]) = k2r;
        } else {
            v8s v0r = *reinterpret_cast<const v8s*>(&Vg[rowb + (0 * 4 + w2) * 8]);
            v8s v1r = *reinterpret_cast<const v8s*>(&Vg[rowb + (1 * 4 + w2) * 8]);
            v8s v2r = *reinterpret_cast<const v8s*>(&Vg[rowb + (2 * 4 + w2) * 8]);
            #pragma unroll
            for (int jj = 0; jj < 8; ++jj) Vt[(0 * 4 + w2) * 8 + jj][lane] = (ushort)v0r[jj];
            #pragma unroll
            for (int jj = 0; jj < 8; ++jj) Vt[(1 * 4 + w2) * 8 + jj][lane] = (ushort)v1r[jj];
            #pragma unroll
            for (int jj = 0; jj < 8; ++jj) Vt[(2 * 4 + w2) * 8 + jj][lane] = (ushort)v2r[jj];
        }
    }
    __syncthreads();

    for (int t = ts; t < te; ++t) {
        const bool have = (t + 1 < te);

        // issue next-tile global->reg loads early (land under compute)
        v8s r0, r1, r2;
        if (have) {
            const size_t rowb = (size_t)((t + 1) * 64 + lane) * DHH;
            if (wv < 4) {
                r0 = *reinterpret_cast<const v8s*>(&Kg[rowb + (w2 * 3 + 0) * 8]);
                r1 = *reinterpret_cast<const v8s*>(&Kg[rowb + (w2 * 3 + 1) * 8]);
                r2 = *reinterpret_cast<const v8s*>(&Kg[rowb + (w2 * 3 + 2) * 8]);
            } else {
                r0 = *reinterpret_cast<const v8s*>(&Vg[rowb + (0 * 4 + w2) * 8]);
                r1 = *reinterpret_cast<const v8s*>(&Vg[rowb + (1 * 4 + w2) * 8]);
                r2 = *reinterpret_cast<const v8s*>(&Vg[rowb + (2 * 4 + w2) * 8]);
            }
        }

        // per ct: S^T = K @ Q^T -> softmax -> PV (exchange-free fragments)
        #pragma unroll
        for (int ct = 0; ct < 2; ++ct) {
            v16f s;
            #pragma unroll
            for (int i = 0; i < 16; ++i) s[i] = 0.0f;
            __builtin_amdgcn_s_setprio(1);
            #pragma unroll
            for (int kt = 0; kt < 6; ++kt) {
                v8s kf = *reinterpret_cast<const v8s*>(
                    &Ks[((kt * 2 + lhi) * 64 + ct * 32 + l31) * 8]);
                s = __builtin_amdgcn_mfma_f32_32x32x16_bf16(kf, qf[kt], s, 0, 0, 0);
            }
            __builtin_amdgcn_s_setprio(0);

            float e[16];
            #pragma unroll
            for (int r = 0; r < 16; ++r) {
                e[r] = exp2f(s[r]);
                ds4[r & 3] += e[r];
            }
            u32 w[8];
            #pragma unroll
            for (int i = 0; i < 8; ++i)
                w[i] = (u32)f2bf(e[2 * i]) | ((u32)f2bf(e[2 * i + 1]) << 16);
            v8s pfA = pack4(w[0], w[1], w[2], w[3]);   // kv offsets {0-3,8-11}
            v8s pfB = pack4(w[4], w[5], w[6], w[7]);   // kv offsets {16-19,24-27}

            __builtin_amdgcn_s_setprio(1);
            #pragma unroll
            for (int dt = 0; dt < 3; ++dt) {
                const ushort* vp = &Vt[dt * 32 + l31][ct * 32 + 4 * lhi];
                v8s vaA = load2x4(vp);        // kv {0-3, 8-11}
                v8s vaB = load2x4(vp + 16);   // kv {16-19, 24-27}
                o[dt] = __builtin_amdgcn_mfma_f32_32x32x16_bf16(vaA, pfA, o[dt], 0, 0, 0);
                o[dt] = __builtin_amdgcn_mfma_f32_32x32x16_bf16(vaB, pfB, o[dt], 0, 0, 0);
            }
            __builtin_amdgcn_s_setprio(0);
        }

        if (have) {
            __syncthreads();   // all waves done READING Ks/Vt
            if (wv < 4) {
                *reinterpret_cast<v8s*>(&Ks[(w2 * 3 + 0) * 512 + lane * 8]) = r0;
                *reinterpret_cast<v8s*>(&Ks[(w2 * 3 + 1) * 512 + lane * 8]) = r1;
                *reinterpret_cast<v8s*>(&Ks[(w2 * 3 + 2) * 512 + lane * 8]) = r2;
            } else {
                #pragma unroll
                for (int jj = 0; jj < 8; ++jj) Vt[(0 * 4 + w2) * 8 + jj][lane] = (ushort)r0[jj];
                #pragma unroll
                for (int jj = 0; jj < 8; ++jj) Vt[(1 * 4 + w2) * 8 + jj][lane] = (ushort)r1[jj];
                #pragma unroll
                for (int jj = 0; jj < 8; ++jj) Vt[(2 * 4 + w2) * 8 + jj][lane] = (ushort)r2[jj];
            }
            __syncthreads();   // writes visible
        }
    }

    // per-half denominator (combine lhi halves); lanes 0-31 write f32 dsum
    float dsum = (ds4[0] + ds4[1]) + (ds4[2] + ds4[3]);
    dsum += __shfl_xor(dsum, 32, 64);
    if (lane < 32)
        dsw[(size_t)half * BH * NN + (size_t)bh * NN + q0 + wv * 32 + lane] = dsum;

    // write RAW O partial (bf16), lane = q row, regs = d
    const int n = q0 + wv * 32 + l31;
    ushort* orow = (half ? O1 : O0) + ((size_t)(b * NN + n)) * DM + h * DHH;
    #pragma unroll
    for (int dt = 0; dt < 3; ++dt) {
        #pragma unroll
        for (int g = 0; g < 4; ++g) {
            const int d0 = dt * 32 + 8 * g + 4 * lhi;
            u32 w0 = (u32)f2bf(o[dt][4 * g + 0]) | ((u32)f2bf(o[dt][4 * g + 1]) << 16);
            u32 w1 = (u32)f2bf(o[dt][4 * g + 2]) | ((u32)f2bf(o[dt][4 * g + 3]) << 16);
            uint2 pk; pk.x = w0; pk.y = w1;
            *reinterpret_cast<uint2*>(&orow[d0]) = pk;
        }
    }
}

// ---------------------------------------------------------------------------
// combine: ao = (O0 + O1) / (d0 + d1), in-place over O1.  8 elems/thread.
// ---------------------------------------------------------------------------
__global__ __launch_bounds__(256)
void combine_kernel(const ushort* __restrict__ O0, ushort* __restrict__ O1io,
                    const float* __restrict__ dsw)
{
    const int i = blockIdx.x * 256 + threadIdx.x;    // 786432 chunks of 8
    const int row = i / 96;                          // 0..8191
    const int c   = i - row * 96;
    const int h   = c / 12;
    const int b   = row >> 11;
    const int n   = row & (NN - 1);
    const int bh  = b * NH + h;
    const float d0 = dsw[(size_t)bh * NN + n];
    const float d1 = dsw[(size_t)BH * NN + (size_t)bh * NN + n];
    const float inv = 1.0f / (d0 + d1);
    v8s a  = *reinterpret_cast<const v8s*>(&O0[(size_t)i * 8]);
    v8s bb = *reinterpret_cast<v8s*>(&O1io[(size_t)i * 8]);
    ushort r[8];
    #pragma unroll
    for (int jj = 0; jj < 8; ++jj)
        r[jj] = f2bf((bf2f((ushort)a[jj]) + bf2f((ushort)bb[jj])) * inv);
    *reinterpret_cast<v8s*>(&O1io[(size_t)i * 8]) = *reinterpret_cast<v8s*>(r);
}

// ---------------------------------------------------------------------------
extern "C" void kernel_launch(void* const* d_in, const int* in_sizes, int n_in,
                              void* d_out, int out_size, void* d_ws, size_t ws_size,
                              hipStream_t stream)
{
    (void)in_sizes; (void)n_in; (void)out_size; (void)ws_size;
    const float* x    = (const float*)d_in[0];
    const float* Wqkv = (const float*)d_in[1];
    const float* bqkv = (const float*)d_in[2];
    const float* Wout = (const float*)d_in[3];
    const float* bout = (const float*)d_in[4];
    float* out = (float*)d_out;

    ushort* qkv   = (ushort*)d_ws;                       // [3][BH][NN][96] bf16
    ushort* ao    = qkv   + (size_t)3 * BH * NN * DHH;   // [8192][768] bf16 (O1 partial -> combined)
    ushort* xbf   = ao    + (size_t)MROWS * DM;          // [8192][768] bf16 (x -> later O0 partial)
    ushort* wqkvt = xbf   + (size_t)MROWS * DM;          // [2304][768] bf16
    ushort* woutt = wqkvt + (size_t)DM * NC_QKV;         // [768][768]  bf16
    float*  dsw   = (float*)(woutt + (size_t)DM * DM);   // [2][BH][NN] f32 dsums

    dim3 blk(256);

    conv_bf16<<<dim3(MROWS * DM / 8 / 256), blk, 0, stream>>>(x, xbf, MROWS * DM / 8);
    convT_bf16<<<dim3(DM / 32, NC_QKV / 32), blk, 0, stream>>>(Wqkv, wqkvt, DM, NC_QKV);
    convT_bf16<<<dim3(DM / 32, DM / 32), blk, 0, stream>>>(Wout, woutt, DM, DM);

    gemm_mfma<1><<<dim3(MROWS / 128, NC_QKV / 128), blk, 0, stream>>>(
        xbf, wqkvt, bqkv, (void*)qkv, DM, NC_QKV);

    // split-KV attention: O0 partial -> xbf (dead after gemm1), O1 -> ao
    attn_mfma<<<dim3(8, 32, 2), dim3(512), 0, stream>>>(qkv, xbf, ao, dsw);

    // normalize + merge halves in-place into ao
    combine_kernel<<<dim3(MROWS * DM / 8 / 256), blk, 0, stream>>>(xbf, ao, dsw);

    gemm_mfma<0><<<dim3(MROWS / 128, DM / 128), blk, 0, stream>>>(
        ao, woutt, bout, (void*)out, DM, DM);
}

// Round 9
// 260.041 us; speedup vs baseline: 1.0041x; 1.0041x over previous
//
#include <hip/hip_runtime.h>
#include <hip/hip_bf16.h>
#include <math.h>

// Problem constants
#define BB      4
#define NN      2048
#define DM      768
#define NH      8
#define DHH     96
#define BH      (BB*NH)          // 32
#define MROWS   (BB*NN)          // 8192
#define NC_QKV  (3*DM)           // 2304

typedef short v4s  __attribute__((ext_vector_type(4)));
typedef short v8s  __attribute__((ext_vector_type(8)));
typedef float v16f __attribute__((ext_vector_type(16)));
typedef unsigned int u32;

// log2(e)/sqrt(96) folded into Q at QKV-GEMM epilogue
#define SCQ 0.14724599350930152f

static __device__ __forceinline__ ushort f2bf(float f) {
    __hip_bfloat16 h = __float2bfloat16(f);
    return *reinterpret_cast<ushort*>(&h);
}
static __device__ __forceinline__ float bf2f(ushort u) {
    u32 x = ((u32)u) << 16;
    return __uint_as_float(x);
}

static __device__ __forceinline__ void gload_lds16(const ushort* g, ushort* l) {
    __builtin_amdgcn_global_load_lds(
        (const __attribute__((address_space(1))) void*)g,
        (__attribute__((address_space(3))) void*)l, 16, 0, 0);
}

// two 8B LDS loads 16B apart -> one v8s fragment (ds_read2_b64)
static __device__ __forceinline__ v8s load2x4(const ushort* p) {
    union { v4s h[2]; v8s s; } x;
    x.h[0] = *reinterpret_cast<const v4s*>(p);
    x.h[1] = *reinterpret_cast<const v4s*>(p + 8);
    return x.s;
}

static __device__ __forceinline__ v8s pack4(u32 a, u32 b, u32 c, u32 d) {
    union { u32 u[4]; v8s s; } x;
    x.u[0] = a; x.u[1] = b; x.u[2] = c; x.u[3] = d;
    return x.s;
}

// ---------------------------------------------------------------------------
// fp32 -> bf16 elementwise (n8 = count/8)
// ---------------------------------------------------------------------------
__global__ __launch_bounds__(256)
void conv_bf16(const float* __restrict__ in, ushort* __restrict__ out, int n8)
{
    int i = blockIdx.x * 256 + threadIdx.x;
    if (i >= n8) return;
    const float4* p = reinterpret_cast<const float4*>(in) + (size_t)i * 2;
    float4 a = p[0], b = p[1];
    ushort r[8] = {f2bf(a.x), f2bf(a.y), f2bf(a.z), f2bf(a.w),
                   f2bf(b.x), f2bf(b.y), f2bf(b.z), f2bf(b.w)};
    *reinterpret_cast<v8s*>(out + (size_t)i * 8) = *reinterpret_cast<v8s*>(r);
}

// ---------------------------------------------------------------------------
// fp32 W[K][N] -> bf16 Wt[N][K] (tiled transpose)
// ---------------------------------------------------------------------------
__global__ __launch_bounds__(256)
void convT_bf16(const float* __restrict__ W, ushort* __restrict__ Wt, int K, int N)
{
    __shared__ ushort t[32][33];
    const int k0 = blockIdx.x * 32, n0 = blockIdx.y * 32;
    const int tx = threadIdx.x & 31, ty = threadIdx.x >> 5;
    #pragma unroll
    for (int r = ty; r < 32; r += 8)
        t[tx][r] = f2bf(W[(size_t)(k0 + r) * N + n0 + tx]);
    __syncthreads();
    #pragma unroll
    for (int r = ty; r < 32; r += 8)
        Wt[(size_t)(n0 + r) * K + k0 + tx] = t[r][tx];
}

// ---------------------------------------------------------------------------
// bf16 MFMA GEMM (unchanged, harness-proven).
// ---------------------------------------------------------------------------
template<int SCATTER>
__global__ __launch_bounds__(256)
void gemm_mfma(const ushort* __restrict__ A, const ushort* __restrict__ Bt,
               const float* __restrict__ bias, void* __restrict__ outp,
               int K, int Ncols)
{
    __shared__ ushort As[2][8192];   // [buf][8 kslots][128 rows][8]
    __shared__ ushort Bs[2][8192];

    const int tid  = threadIdx.x;
    const int lane = tid & 63;
    const int wv   = tid >> 6;
    const int l31  = lane & 31;
    const int lhi  = lane >> 5;
    const int wr   = wv >> 1, wc = wv & 1;

    const int ny   = gridDim.y;
    const int id   = blockIdx.y * gridDim.x + blockIdx.x;
    const int c8   = id & 7;
    const int j    = id >> 3;
    const int hy   = (j >= (ny >> 1) * 8) ? 1 : 0;
    const int w    = j - hy * (ny >> 1) * 8;
    const int bx   = c8 * 8 + (w & 7);
    const int by   = hy * (ny >> 1) + (w >> 3);
    const int row0 = bx * 128;
    const int col0 = by * 128;

    v16f acc[2][2];
    #pragma unroll
    for (int mi = 0; mi < 2; ++mi)
        #pragma unroll
        for (int nj = 0; nj < 2; ++nj)
            #pragma unroll
            for (int i = 0; i < 16; ++i) acc[mi][nj][i] = 0.0f;

#define STAGE_G(bsel, kk) do {                                                  \
    _Pragma("unroll")                                                           \
    for (int c = 0; c < 4; ++c) {                                               \
        const int g   = c * 4 + wv;                                             \
        const int idx = g * 64 + lane;                                          \
        const int ss  = idx >> 7, rr = idx & 127;                               \
        gload_lds16(&A [(size_t)(row0 + rr) * K + (kk) + ss * 8],               \
                    &As[bsel][g * 512]);                                        \
        gload_lds16(&Bt[(size_t)(col0 + rr) * K + (kk) + ss * 8],               \
                    &Bs[bsel][g * 512]);                                        \
    }                                                                           \
} while (0)

    STAGE_G(0, 0);
    __syncthreads();

    const int nk = K >> 6;
    for (int t = 0; t < nk; ++t) {
        const int cur = t & 1;
        if (t + 1 < nk) STAGE_G(cur ^ 1, (t + 1) << 6);

        #pragma unroll
        for (int s16 = 0; s16 < 4; ++s16) {
            const int ks = s16 * 2 + lhi;
            v8s a0 = *reinterpret_cast<const v8s*>(&As[cur][(size_t)(ks * 128 + 64 * wr + l31) * 8]);
            v8s a1 = *reinterpret_cast<const v8s*>(&As[cur][(size_t)(ks * 128 + 64 * wr + 32 + l31) * 8]);
            v8s b0 = *reinterpret_cast<const v8s*>(&Bs[cur][(size_t)(ks * 128 + 64 * wc + l31) * 8]);
            v8s b1 = *reinterpret_cast<const v8s*>(&Bs[cur][(size_t)(ks * 128 + 64 * wc + 32 + l31) * 8]);
            acc[0][0] = __builtin_amdgcn_mfma_f32_32x32x16_bf16(a0, b0, acc[0][0], 0, 0, 0);
            acc[0][1] = __builtin_amdgcn_mfma_f32_32x32x16_bf16(a0, b1, acc[0][1], 0, 0, 0);
            acc[1][0] = __builtin_amdgcn_mfma_f32_32x32x16_bf16(a1, b0, acc[1][0], 0, 0, 0);
            acc[1][1] = __builtin_amdgcn_mfma_f32_32x32x16_bf16(a1, b1, acc[1][1], 0, 0, 0);
        }
        __syncthreads();
    }
#undef STAGE_G

    #pragma unroll
    for (int nj = 0; nj < 2; ++nj) {
        const int c = col0 + 64 * wc + 32 * nj + l31;
        const float bv = bias[c];
        #pragma unroll
        for (int mi = 0; mi < 2; ++mi) {
            #pragma unroll
            for (int r = 0; r < 16; ++r) {
                const int m = row0 + 64 * wr + 32 * mi + (r & 3) + 8 * (r >> 2) + 4 * lhi;
                float v = acc[mi][nj][r] + bv;
                if (SCATTER) {
                    const int s   = c / DM;
                    const int rem = c - s * DM;
                    const int h   = rem / DHH;
                    const int d   = rem - h * DHH;
                    const int b   = m >> 11;
                    const int n   = m & (NN - 1);
                    if (s == 0) v *= SCQ;
                    ((ushort*)outp)[((size_t)(s * BH + b * NH + h) * NN + n) * DHH + d] = f2bf(v);
                } else {
                    ((float*)outp)[(size_t)m * Ncols + c] = v;
                }
            }
        }
    }
}

// ---------------------------------------------------------------------------
// Split-KV MFMA bf16 flash attention (round-8 compute structure, frozen).
// CHANGED: O-partial stored TRANSPOSED as OT[half][bh][d][n] bf16 so lane
// (=n) is the fastest axis -> every store merges into full 64B lines.
// (Round 8's n-major partial writes didn't merge: 185 MB HBM writes whose
// write-allocate traffic evicted qkv from L3 -> 249 MB re-fetch.)
// ---------------------------------------------------------------------------
__global__ __launch_bounds__(512, 4)
void attn_mfma(const ushort* __restrict__ qkv, ushort* __restrict__ OT,
               float* __restrict__ dsw)
{
    __shared__ ushort Ks[6144];        // [kslot g=12][kv=64][8]
    __shared__ ushort Vt[96][68];      // [d][kv], pad 68 (2-way, free)

    const int tid  = threadIdx.x;
    const int lane = tid & 63;
    const int wv   = tid >> 6;          // 0..7
    const int w2   = wv & 3;
    const int l31  = lane & 31;
    const int lhi  = lane >> 5;

    const int id   = blockIdx.z * (gridDim.x * gridDim.y)
                   + blockIdx.y * gridDim.x + blockIdx.x;   // 0..511
    const int c8   = id & 7;
    const int j    = id >> 3;            // 0..63
    const int bh   = c8 * 4 + (j & 3);
    const int qt   = (j >> 2) & 7;
    const int half = j >> 5;
    const int q0   = qt * 256;

    const ushort* Qg = qkv + (size_t)bh * NN * DHH;
    const ushort* Kg = qkv + ((size_t)BH + bh) * NN * DHH;
    const ushort* Vg = qkv + ((size_t)2 * BH + bh) * NN * DHH;

    // Q fragments (pre-scaled by SCQ): q row = q0 + wv*32 + l31
    const int qr = q0 + wv * 32 + l31;
    v8s qf[6];
    #pragma unroll
    for (int kt = 0; kt < 6; ++kt)
        qf[kt] = *reinterpret_cast<const v8s*>(&Qg[(size_t)qr * DHH + kt * 16 + lhi * 8]);

    v16f o[3];
    #pragma unroll
    for (int dt = 0; dt < 3; ++dt)
        #pragma unroll
        for (int i = 0; i < 16; ++i) o[dt][i] = 0.0f;
    float ds4[4] = {0.0f, 0.0f, 0.0f, 0.0f};

    const int ts = half * 16, te = ts + 16;

    // ---- prologue: stage tile ts (K: waves 0-3, V: waves 4-7)
    {
        const size_t rowb = (size_t)(ts * 64 + lane) * DHH;
        if (wv < 4) {
            v8s k0r = *reinterpret_cast<const v8s*>(&Kg[rowb + (w2 * 3 + 0) * 8]);
            v8s k1r = *reinterpret_cast<const v8s*>(&Kg[rowb + (w2 * 3 + 1) * 8]);
            v8s k2r = *reinterpret_cast<const v8s*>(&Kg[rowb + (w2 * 3 + 2) * 8]);
            *reinterpret_cast<v8s*>(&Ks[(w2 * 3 + 0) * 512 + lane * 8]) = k0r;
            *reinterpret_cast<v8s*>(&Ks[(w2 * 3 + 1) * 512 + lane * 8]) = k1r;
            *reinterpret_cast<v8s*>(&Ks[(w2 * 3 + 2) * 512 + lane * 8]) = k2r;
        } else {
            v8s v0r = *reinterpret_cast<const v8s*>(&Vg[rowb + (0 * 4 + w2) * 8]);
            v8s v1r = *reinterpret_cast<const v8s*>(&Vg[rowb + (1 * 4 + w2) * 8]);
            v8s v2r = *reinterpret_cast<const v8s*>(&Vg[rowb + (2 * 4 + w2) * 8]);
            #pragma unroll
            for (int jj = 0; jj < 8; ++jj) Vt[(0 * 4 + w2) * 8 + jj][lane] = (ushort)v0r[jj];
            #pragma unroll
            for (int jj = 0; jj < 8; ++jj) Vt[(1 * 4 + w2) * 8 + jj][lane] = (ushort)v1r[jj];
            #pragma unroll
            for (int jj = 0; jj < 8; ++jj) Vt[(2 * 4 + w2) * 8 + jj][lane] = (ushort)v2r[jj];
        }
    }
    __syncthreads();

    for (int t = ts; t < te; ++t) {
        const bool have = (t + 1 < te);

        // issue next-tile global->reg loads early (land under compute)
        v8s r0, r1, r2;
        if (have) {
            const size_t rowb = (size_t)((t + 1) * 64 + lane) * DHH;
            if (wv < 4) {
                r0 = *reinterpret_cast<const v8s*>(&Kg[rowb + (w2 * 3 + 0) * 8]);
                r1 = *reinterpret_cast<const v8s*>(&Kg[rowb + (w2 * 3 + 1) * 8]);
                r2 = *reinterpret_cast<const v8s*>(&Kg[rowb + (w2 * 3 + 2) * 8]);
            } else {
                r0 = *reinterpret_cast<const v8s*>(&Vg[rowb + (0 * 4 + w2) * 8]);
                r1 = *reinterpret_cast<const v8s*>(&Vg[rowb + (1 * 4 + w2) * 8]);
                r2 = *reinterpret_cast<const v8s*>(&Vg[rowb + (2 * 4 + w2) * 8]);
            }
        }

        // per ct: S^T = K @ Q^T -> softmax -> PV (exchange-free fragments)
        #pragma unroll
        for (int ct = 0; ct < 2; ++ct) {
            v16f s;
            #pragma unroll
            for (int i = 0; i < 16; ++i) s[i] = 0.0f;
            __builtin_amdgcn_s_setprio(1);
            #pragma unroll
            for (int kt = 0; kt < 6; ++kt) {
                v8s kf = *reinterpret_cast<const v8s*>(
                    &Ks[((kt * 2 + lhi) * 64 + ct * 32 + l31) * 8]);
                s = __builtin_amdgcn_mfma_f32_32x32x16_bf16(kf, qf[kt], s, 0, 0, 0);
            }
            __builtin_amdgcn_s_setprio(0);

            float e[16];
            #pragma unroll
            for (int r = 0; r < 16; ++r) {
                e[r] = exp2f(s[r]);
                ds4[r & 3] += e[r];
            }
            u32 w[8];
            #pragma unroll
            for (int i = 0; i < 8; ++i)
                w[i] = (u32)f2bf(e[2 * i]) | ((u32)f2bf(e[2 * i + 1]) << 16);
            v8s pfA = pack4(w[0], w[1], w[2], w[3]);   // kv offsets {0-3,8-11}
            v8s pfB = pack4(w[4], w[5], w[6], w[7]);   // kv offsets {16-19,24-27}

            __builtin_amdgcn_s_setprio(1);
            #pragma unroll
            for (int dt = 0; dt < 3; ++dt) {
                const ushort* vp = &Vt[dt * 32 + l31][ct * 32 + 4 * lhi];
                v8s vaA = load2x4(vp);        // kv {0-3, 8-11}
                v8s vaB = load2x4(vp + 16);   // kv {16-19, 24-27}
                o[dt] = __builtin_amdgcn_mfma_f32_32x32x16_bf16(vaA, pfA, o[dt], 0, 0, 0);
                o[dt] = __builtin_amdgcn_mfma_f32_32x32x16_bf16(vaB, pfB, o[dt], 0, 0, 0);
            }
            __builtin_amdgcn_s_setprio(0);
        }

        if (have) {
            __syncthreads();   // all waves done READING Ks/Vt
            if (wv < 4) {
                *reinterpret_cast<v8s*>(&Ks[(w2 * 3 + 0) * 512 + lane * 8]) = r0;
                *reinterpret_cast<v8s*>(&Ks[(w2 * 3 + 1) * 512 + lane * 8]) = r1;
                *reinterpret_cast<v8s*>(&Ks[(w2 * 3 + 2) * 512 + lane * 8]) = r2;
            } else {
                #pragma unroll
                for (int jj = 0; jj < 8; ++jj) Vt[(0 * 4 + w2) * 8 + jj][lane] = (ushort)r0[jj];
                #pragma unroll
                for (int jj = 0; jj < 8; ++jj) Vt[(1 * 4 + w2) * 8 + jj][lane] = (ushort)r1[jj];
                #pragma unroll
                for (int jj = 0; jj < 8; ++jj) Vt[(2 * 4 + w2) * 8 + jj][lane] = (ushort)r2[jj];
            }
            __syncthreads();   // writes visible
        }
    }

    // per-half denominator (combine lhi halves); lanes 0-31 write f32 dsum
    float dsum = (ds4[0] + ds4[1]) + (ds4[2] + ds4[3]);
    dsum += __shfl_xor(dsum, 32, 64);
    if (lane < 32)
        dsw[(size_t)half * BH * NN + (size_t)bh * NN + q0 + wv * 32 + lane] = dsum;

    // write RAW O^T partial (bf16): OT[half][bh][d][n], lane = n -> coalesced
    ushort* OTb = OT + ((size_t)half * BH + bh) * ((size_t)DHH * NN);
    const int n = q0 + wv * 32 + l31;
    #pragma unroll
    for (int dt = 0; dt < 3; ++dt) {
        #pragma unroll
        for (int g = 0; g < 4; ++g) {
            #pragma unroll
            for (int jj = 0; jj < 4; ++jj) {
                const int d = dt * 32 + 8 * g + 4 * lhi + jj;
                OTb[(size_t)d * NN + n] = f2bf(o[dt][4 * g + jj]);
            }
        }
    }
}

// ---------------------------------------------------------------------------
// combine + transpose: ao[b*NN+n][h*96+d] = (OT0[d][n]+OT1[d][n])/(d0+d1)
// convT-style 32x32 LDS tile; reads and writes both coalesced.
// grid = (NN/32, DHH/32, BH)
// ---------------------------------------------------------------------------
__global__ __launch_bounds__(256)
void combineT_kernel(const ushort* __restrict__ OT, const float* __restrict__ dsw,
                     ushort* __restrict__ ao)
{
    __shared__ float t[32][33];
    const int n0 = blockIdx.x * 32;
    const int d0 = blockIdx.y * 32;
    const int bh = blockIdx.z;
    const int b = bh >> 3, h = bh & 7;
    const int tx = threadIdx.x & 31, ty = threadIdx.x >> 5;

    const ushort* O0 = OT + (size_t)bh * DHH * NN;
    const ushort* O1 = OT + (size_t)(BH + bh) * DHH * NN;
    const int n = n0 + tx;
    const float inv = 1.0f /
        (dsw[(size_t)bh * NN + n] + dsw[(size_t)BH * NN + (size_t)bh * NN + n]);

    #pragma unroll
    for (int r = ty; r < 32; r += 8) {
        const size_t off = (size_t)(d0 + r) * NN + n;
        t[tx][r] = (bf2f(O0[off]) + bf2f(O1[off])) * inv;
    }
    __syncthreads();
    #pragma unroll
    for (int r = ty; r < 32; r += 8)
        ao[(size_t)(b * NN + n0 + r) * DM + h * DHH + d0 + tx] = f2bf(t[r][tx]);
}

// ---------------------------------------------------------------------------
extern "C" void kernel_launch(void* const* d_in, const int* in_sizes, int n_in,
                              void* d_out, int out_size, void* d_ws, size_t ws_size,
                              hipStream_t stream)
{
    (void)in_sizes; (void)n_in; (void)out_size; (void)ws_size;
    const float* x    = (const float*)d_in[0];
    const float* Wqkv = (const float*)d_in[1];
    const float* bqkv = (const float*)d_in[2];
    const float* Wout = (const float*)d_in[3];
    const float* bout = (const float*)d_in[4];
    float* out = (float*)d_out;

    ushort* qkv   = (ushort*)d_ws;                       // [3][BH][NN][96] bf16
    ushort* ao    = qkv   + (size_t)3 * BH * NN * DHH;   // [8192][768] bf16 combined attn out
    ushort* xbf   = ao    + (size_t)MROWS * DM;          // [8192][768] bf16 x
    ushort* wqkvt = xbf   + (size_t)MROWS * DM;          // [2304][768] bf16
    ushort* woutt = wqkvt + (size_t)DM * NC_QKV;         // [768][768]  bf16
    float*  dsw   = (float*)(woutt + (size_t)DM * DM);   // [2][BH][NN] f32
    ushort* OT    = (ushort*)(dsw + (size_t)2 * BH * NN);// [2][BH][96][NN] bf16 partials

    dim3 blk(256);

    conv_bf16<<<dim3(MROWS * DM / 8 / 256), blk, 0, stream>>>(x, xbf, MROWS * DM / 8);
    convT_bf16<<<dim3(DM / 32, NC_QKV / 32), blk, 0, stream>>>(Wqkv, wqkvt, DM, NC_QKV);
    convT_bf16<<<dim3(DM / 32, DM / 32), blk, 0, stream>>>(Wout, woutt, DM, DM);

    gemm_mfma<1><<<dim3(MROWS / 128, NC_QKV / 128), blk, 0, stream>>>(
        xbf, wqkvt, bqkv, (void*)qkv, DM, NC_QKV);

    // split-KV attention -> transposed bf16 partials + f32 dsums
    attn_mfma<<<dim3(8, 32, 2), dim3(512), 0, stream>>>(qkv, OT, dsw);

    // normalize + merge + transpose into ao
    combineT_kernel<<<dim3(NN / 32, DHH / 32, BH), blk, 0, stream>>>(OT, dsw, ao);

    gemm_mfma<0><<<dim3(MROWS / 128, DM / 128), blk, 0, stream>>>(
        ao, woutt, bout, (void*)out, DM, DM);
}

// Round 10
// 211.872 us; speedup vs baseline: 1.2324x; 1.2273x over previous
//
#include <hip/hip_runtime.h>
#include <hip/hip_bf16.h>
#include <math.h>

// Problem constants
#define BB      4
#define NN      2048
#define DM      768
#define NH      8
#define DHH     96
#define BH      (BB*NH)          // 32
#define MROWS   (BB*NN)          // 8192
#define NC_QKV  (3*DM)           // 2304

typedef short v4s  __attribute__((ext_vector_type(4)));
typedef short v8s  __attribute__((ext_vector_type(8)));
typedef float v16f __attribute__((ext_vector_type(16)));
typedef unsigned int u32;

// log2(e)/sqrt(96) folded into Q at QKV-GEMM epilogue
#define SCQ 0.14724599350930152f

static __device__ __forceinline__ ushort f2bf(float f) {
    __hip_bfloat16 h = __float2bfloat16(f);
    return *reinterpret_cast<ushort*>(&h);
}

static __device__ __forceinline__ void gload_lds16(const ushort* g, ushort* l) {
    __builtin_amdgcn_global_load_lds(
        (const __attribute__((address_space(1))) void*)g,
        (__attribute__((address_space(3))) void*)l, 16, 0, 0);
}

// two 8B LDS loads 16B apart -> one v8s fragment (ds_read2_b64)
static __device__ __forceinline__ v8s load2x4(const ushort* p) {
    union { v4s h[2]; v8s s; } x;
    x.h[0] = *reinterpret_cast<const v4s*>(p);
    x.h[1] = *reinterpret_cast<const v4s*>(p + 8);
    return x.s;
}

static __device__ __forceinline__ v8s pack4(u32 a, u32 b, u32 c, u32 d) {
    union { u32 u[4]; v8s s; } x;
    x.u[0] = a; x.u[1] = b; x.u[2] = c; x.u[3] = d;
    return x.s;
}

// ---------------------------------------------------------------------------
// fp32 -> bf16 elementwise (n8 = count/8)
// ---------------------------------------------------------------------------
__global__ __launch_bounds__(256)
void conv_bf16(const float* __restrict__ in, ushort* __restrict__ out, int n8)
{
    int i = blockIdx.x * 256 + threadIdx.x;
    if (i >= n8) return;
    const float4* p = reinterpret_cast<const float4*>(in) + (size_t)i * 2;
    float4 a = p[0], b = p[1];
    ushort r[8] = {f2bf(a.x), f2bf(a.y), f2bf(a.z), f2bf(a.w),
                   f2bf(b.x), f2bf(b.y), f2bf(b.z), f2bf(b.w)};
    *reinterpret_cast<v8s*>(out + (size_t)i * 8) = *reinterpret_cast<v8s*>(r);
}

// ---------------------------------------------------------------------------
// fp32 W[K][N] -> bf16 Wt[N][K] (tiled transpose)
// ---------------------------------------------------------------------------
__global__ __launch_bounds__(256)
void convT_bf16(const float* __restrict__ W, ushort* __restrict__ Wt, int K, int N)
{
    __shared__ ushort t[32][33];
    const int k0 = blockIdx.x * 32, n0 = blockIdx.y * 32;
    const int tx = threadIdx.x & 31, ty = threadIdx.x >> 5;
    #pragma unroll
    for (int r = ty; r < 32; r += 8)
        t[tx][r] = f2bf(W[(size_t)(k0 + r) * N + n0 + tx]);
    __syncthreads();
    #pragma unroll
    for (int r = ty; r < 32; r += 8)
        Wt[(size_t)(n0 + r) * K + k0 + tx] = t[r][tx];
}

// ---------------------------------------------------------------------------
// bf16 MFMA GEMM: C[M][Ncols] = A[M][K] @ Bt[Ncols][K]^T + bias
// T4 counted-vmcnt pipeline (m201/m218 protocol, minimal instance):
//   per K-step: STAGE(t+1) [8 gload_lds/thread]; s_waitcnt vmcnt(8)
//   (tile t landed, t+1 still in flight); s_barrier; compute(t); s_barrier.
// Loads cross the barriers -- no full vmcnt(0) drain in the main loop.
// Last iteration waits vmcnt(0). Uniform control flow (nk even, same for
// all blocks) -> no barrier divergence.
// SCATTER=1: bf16 into qkv [3][BH][N][96] (Q pre-scaled by SCQ);
// SCATTER=0: fp32 row-major.
// ---------------------------------------------------------------------------
template<int SCATTER>
__global__ __launch_bounds__(256)
void gemm_mfma(const ushort* __restrict__ A, const ushort* __restrict__ Bt,
               const float* __restrict__ bias, void* __restrict__ outp,
               int K, int Ncols)
{
    __shared__ ushort As[2][8192];   // [buf][8 kslots][128 rows][8]
    __shared__ ushort Bs[2][8192];

    const int tid  = threadIdx.x;
    const int lane = tid & 63;
    const int wv   = tid >> 6;
    const int l31  = lane & 31;
    const int lhi  = lane >> 5;
    const int wr   = wv >> 1, wc = wv & 1;

    // XCD supertile swizzle (gridDim.x==64, gridDim.y even)
    const int ny   = gridDim.y;
    const int id   = blockIdx.y * gridDim.x + blockIdx.x;
    const int c8   = id & 7;
    const int j    = id >> 3;
    const int hy   = (j >= (ny >> 1) * 8) ? 1 : 0;
    const int w    = j - hy * (ny >> 1) * 8;
    const int bx   = c8 * 8 + (w & 7);
    const int by   = hy * (ny >> 1) + (w >> 3);
    const int row0 = bx * 128;
    const int col0 = by * 128;

    v16f acc[2][2];
    #pragma unroll
    for (int mi = 0; mi < 2; ++mi)
        #pragma unroll
        for (int nj = 0; nj < 2; ++nj)
            #pragma unroll
            for (int i = 0; i < 16; ++i) acc[mi][nj][i] = 0.0f;

#define STAGE_G(bsel, kk) do {                                                  \
    _Pragma("unroll")                                                           \
    for (int c = 0; c < 4; ++c) {                                               \
        const int g   = c * 4 + wv;                                             \
        const int idx = g * 64 + lane;                                          \
        const int ss  = idx >> 7, rr = idx & 127;                               \
        gload_lds16(&A [(size_t)(row0 + rr) * K + (kk) + ss * 8],               \
                    &As[bsel][g * 512]);                                        \
        gload_lds16(&Bt[(size_t)(col0 + rr) * K + (kk) + ss * 8],               \
                    &Bs[bsel][g * 512]);                                        \
    }                                                                           \
} while (0)

    STAGE_G(0, 0);   // tile 0 in flight (8 loads/thread)

    const int nk = K >> 6;
    for (int t = 0; t < nk; ++t) {
        const int cur = t & 1;
        if (t + 1 < nk) {
            STAGE_G(cur ^ 1, (t + 1) << 6);                 // +8 in flight
            asm volatile("s_waitcnt vmcnt(8)" ::: "memory"); // tile t landed
        } else {
            asm volatile("s_waitcnt vmcnt(0)" ::: "memory"); // drain last tile
        }
        __builtin_amdgcn_s_barrier();   // all waves' tile-t DMA visible

        #pragma unroll
        for (int s16 = 0; s16 < 4; ++s16) {
            const int ks = s16 * 2 + lhi;
            v8s a0 = *reinterpret_cast<const v8s*>(&As[cur][(size_t)(ks * 128 + 64 * wr + l31) * 8]);
            v8s a1 = *reinterpret_cast<const v8s*>(&As[cur][(size_t)(ks * 128 + 64 * wr + 32 + l31) * 8]);
            v8s b0 = *reinterpret_cast<const v8s*>(&Bs[cur][(size_t)(ks * 128 + 64 * wc + l31) * 8]);
            v8s b1 = *reinterpret_cast<const v8s*>(&Bs[cur][(size_t)(ks * 128 + 64 * wc + 32 + l31) * 8]);
            acc[0][0] = __builtin_amdgcn_mfma_f32_32x32x16_bf16(a0, b0, acc[0][0], 0, 0, 0);
            acc[0][1] = __builtin_amdgcn_mfma_f32_32x32x16_bf16(a0, b1, acc[0][1], 0, 0, 0);
            acc[1][0] = __builtin_amdgcn_mfma_f32_32x32x16_bf16(a1, b0, acc[1][0], 0, 0, 0);
            acc[1][1] = __builtin_amdgcn_mfma_f32_32x32x16_bf16(a1, b1, acc[1][1], 0, 0, 0);
        }
        __builtin_amdgcn_s_barrier();   // all waves done reading buf[cur]
    }
#undef STAGE_G

    #pragma unroll
    for (int nj = 0; nj < 2; ++nj) {
        const int c = col0 + 64 * wc + 32 * nj + l31;
        const float bv = bias[c];
        #pragma unroll
        for (int mi = 0; mi < 2; ++mi) {
            #pragma unroll
            for (int r = 0; r < 16; ++r) {
                const int m = row0 + 64 * wr + 32 * mi + (r & 3) + 8 * (r >> 2) + 4 * lhi;
                float v = acc[mi][nj][r] + bv;
                if (SCATTER) {
                    const int s   = c / DM;
                    const int rem = c - s * DM;
                    const int h   = rem / DHH;
                    const int d   = rem - h * DHH;
                    const int b   = m >> 11;
                    const int n   = m & (NN - 1);
                    if (s == 0) v *= SCQ;
                    ((ushort*)outp)[((size_t)(s * BH + b * NH + h) * NN + n) * DHH + d] = f2bf(v);
                } else {
                    ((float*)outp)[(size_t)m * Ncols + c] = v;
                }
            }
        }
    }
}

// ---------------------------------------------------------------------------
// MFMA bf16 flash attention (round-7 proven kernel, restored verbatim).
// Swapped QK^T, in-register P via shared k-permutation, reg-staged
// double-buffered K/V, one barrier per tile, setprio on MFMA clusters,
// bh-clustered XCD swizzle.
// ---------------------------------------------------------------------------
__global__ __launch_bounds__(256)
void attn_mfma(const ushort* __restrict__ qkv, ushort* __restrict__ attnout)
{
    __shared__ ushort Ks[2][6144];     // [buf][kslot g=12][kv=64][8]
    __shared__ ushort Vt[2][96][72];   // [buf][d][kv], pad 8

    const int tid  = threadIdx.x;
    const int lane = tid & 63;
    const int wv   = tid >> 6;
    const int l31  = lane & 31;
    const int lhi  = lane >> 5;

    // bh-clustered XCD swizzle (grid = (16, 32))
    const int id   = blockIdx.y * gridDim.x + blockIdx.x;
    const int c8   = id & 7;
    const int j    = id >> 3;            // 0..63
    const int bh   = c8 * 4 + (j >> 4);
    const int q0   = (j & 15) * 128;
    const int b    = bh >> 3, h = bh & 7;

    const ushort* Qg = qkv + (size_t)bh * NN * DHH;
    const ushort* Kg = qkv + ((size_t)BH + bh) * NN * DHH;
    const ushort* Vg = qkv + ((size_t)2 * BH + bh) * NN * DHH;

    // Q fragments (pre-scaled by SCQ in GEMM): q row = q0 + wv*32 + l31
    const int qr = q0 + wv * 32 + l31;
    v8s qf[6];
    #pragma unroll
    for (int kt = 0; kt < 6; ++kt)
        qf[kt] = *reinterpret_cast<const v8s*>(&Qg[(size_t)qr * DHH + kt * 16 + lhi * 8]);

    v16f o[3];
    #pragma unroll
    for (int dt = 0; dt < 3; ++dt)
        #pragma unroll
        for (int i = 0; i < 16; ++i) o[dt][i] = 0.0f;
    float ds4[4] = {0.0f, 0.0f, 0.0f, 0.0f};

    // ---- prologue: reg-stage tile 0 into buf 0
    {
        v8s kr[3], vr[3];
        #pragma unroll
        for (int i = 0; i < 3; ++i) {
            kr[i] = *reinterpret_cast<const v8s*>(&Kg[(size_t)lane * DHH + (wv * 3 + i) * 8]);
            vr[i] = *reinterpret_cast<const v8s*>(&Vg[(size_t)lane * DHH + (i * 4 + wv) * 8]);
        }
        #pragma unroll
        for (int i = 0; i < 3; ++i) {
            *reinterpret_cast<v8s*>(&Ks[0][(wv * 3 + i) * 512 + lane * 8]) = kr[i];
            #pragma unroll
            for (int j2 = 0; j2 < 8; ++j2)
                Vt[0][(i * 4 + wv) * 8 + j2][lane] = (ushort)vr[i][j2];
        }
    }
    __syncthreads();

    for (int t = 0; t < 32; ++t) {
        const int cur = t & 1, nxt = cur ^ 1;
        const int kbase = (t + 1) * 64;

        // issue next-tile global->reg loads early (land under compute)
        v8s kr0, kr1, kr2, vr0, vr1, vr2;
        if (t < 31) {
            const ushort* krow = &Kg[(size_t)(kbase + lane) * DHH];
            const ushort* vrow = &Vg[(size_t)(kbase + lane) * DHH];
            kr0 = *reinterpret_cast<const v8s*>(&krow[(wv * 3 + 0) * 8]);
            kr1 = *reinterpret_cast<const v8s*>(&krow[(wv * 3 + 1) * 8]);
            kr2 = *reinterpret_cast<const v8s*>(&krow[(wv * 3 + 2) * 8]);
            vr0 = *reinterpret_cast<const v8s*>(&vrow[(0 * 4 + wv) * 8]);
            vr1 = *reinterpret_cast<const v8s*>(&vrow[(1 * 4 + wv) * 8]);
            vr2 = *reinterpret_cast<const v8s*>(&vrow[(2 * 4 + wv) * 8]);
        }

        // per ct: S^T = K @ Q^T -> softmax -> PV (exchange-free fragments)
        #pragma unroll
        for (int ct = 0; ct < 2; ++ct) {
            v16f s;
            #pragma unroll
            for (int i = 0; i < 16; ++i) s[i] = 0.0f;
            __builtin_amdgcn_s_setprio(1);
            #pragma unroll
            for (int kt = 0; kt < 6; ++kt) {
                v8s kf = *reinterpret_cast<const v8s*>(
                    &Ks[cur][((kt * 2 + lhi) * 64 + ct * 32 + l31) * 8]);
                s = __builtin_amdgcn_mfma_f32_32x32x16_bf16(kf, qf[kt], s, 0, 0, 0);
            }
            __builtin_amdgcn_s_setprio(0);

            // exp + 4-way denom accumulate + direct pack:
            // e[r] = P[kv = ct*32 + (r&3)+8*(r>>2)+4*lhi][q=l31]
            float e[16];
            #pragma unroll
            for (int r = 0; r < 16; ++r) {
                e[r] = exp2f(s[r]);
                ds4[r & 3] += e[r];
            }
            u32 w[8];
            #pragma unroll
            for (int i = 0; i < 8; ++i)
                w[i] = (u32)f2bf(e[2 * i]) | ((u32)f2bf(e[2 * i + 1]) << 16);
            v8s pfA = pack4(w[0], w[1], w[2], w[3]);   // kv offsets {0-3,8-11}
            v8s pfB = pack4(w[4], w[5], w[6], w[7]);   // kv offsets {16-19,24-27}

            // PV: A = V^T with the SAME k-permutation (two b64 reads each)
            __builtin_amdgcn_s_setprio(1);
            #pragma unroll
            for (int dt = 0; dt < 3; ++dt) {
                const ushort* vp = &Vt[cur][dt * 32 + l31][ct * 32 + 4 * lhi];
                v8s vaA = load2x4(vp);        // kv {0-3, 8-11}
                v8s vaB = load2x4(vp + 16);   // kv {16-19, 24-27}
                o[dt] = __builtin_amdgcn_mfma_f32_32x32x16_bf16(vaA, pfA, o[dt], 0, 0, 0);
                o[dt] = __builtin_amdgcn_mfma_f32_32x32x16_bf16(vaB, pfB, o[dt], 0, 0, 0);
            }
            __builtin_amdgcn_s_setprio(0);
        }

        // write next K/V tiles into LDS (loads landed under compute)
        if (t < 31) {
            *reinterpret_cast<v8s*>(&Ks[nxt][(wv * 3 + 0) * 512 + lane * 8]) = kr0;
            *reinterpret_cast<v8s*>(&Ks[nxt][(wv * 3 + 1) * 512 + lane * 8]) = kr1;
            *reinterpret_cast<v8s*>(&Ks[nxt][(wv * 3 + 2) * 512 + lane * 8]) = kr2;
            #pragma unroll
            for (int j2 = 0; j2 < 8; ++j2) Vt[nxt][(0 * 4 + wv) * 8 + j2][lane] = (ushort)vr0[j2];
            #pragma unroll
            for (int j2 = 0; j2 < 8; ++j2) Vt[nxt][(1 * 4 + wv) * 8 + j2][lane] = (ushort)vr1[j2];
            #pragma unroll
            for (int j2 = 0; j2 < 8; ++j2) Vt[nxt][(2 * 4 + wv) * 8 + j2][lane] = (ushort)vr2[j2];
        }
        __syncthreads();
    }

    // final denominator: combine 4 accumulators + the two lhi halves
    float dsum = (ds4[0] + ds4[1]) + (ds4[2] + ds4[3]);
    dsum += __shfl_xor(dsum, 32, 64);
    const float inv = 1.0f / dsum;

    // write O^T: lane = q row, regs = d (pack 4 bf16 = 8B stores)
    const int n = q0 + wv * 32 + l31;
    ushort* orow = attnout + ((size_t)(b * NN + n)) * DM + h * DHH;
    #pragma unroll
    for (int dt = 0; dt < 3; ++dt) {
        #pragma unroll
        for (int g = 0; g < 4; ++g) {
            const int d0 = dt * 32 + 8 * g + 4 * lhi;
            u32 w0 = (u32)f2bf(o[dt][4 * g + 0] * inv) | ((u32)f2bf(o[dt][4 * g + 1] * inv) << 16);
            u32 w1 = (u32)f2bf(o[dt][4 * g + 2] * inv) | ((u32)f2bf(o[dt][4 * g + 3] * inv) << 16);
            uint2 pk; pk.x = w0; pk.y = w1;
            *reinterpret_cast<uint2*>(&orow[d0]) = pk;
        }
    }
}

// ---------------------------------------------------------------------------
extern "C" void kernel_launch(void* const* d_in, const int* in_sizes, int n_in,
                              void* d_out, int out_size, void* d_ws, size_t ws_size,
                              hipStream_t stream)
{
    (void)in_sizes; (void)n_in; (void)out_size; (void)ws_size;
    const float* x    = (const float*)d_in[0];
    const float* Wqkv = (const float*)d_in[1];
    const float* bqkv = (const float*)d_in[2];
    const float* Wout = (const float*)d_in[3];
    const float* bout = (const float*)d_in[4];
    float* out = (float*)d_out;

    ushort* qkv   = (ushort*)d_ws;                       // [3][BH][NN][96] bf16
    ushort* ao    = qkv   + (size_t)3 * BH * NN * DHH;   // [8192][768] bf16
    ushort* xbf   = ao    + (size_t)MROWS * DM;          // [8192][768] bf16
    ushort* wqkvt = xbf   + (size_t)MROWS * DM;          // [2304][768] bf16
    ushort* woutt = wqkvt + (size_t)DM * NC_QKV;         // [768][768]  bf16

    dim3 blk(256);

    conv_bf16<<<dim3(MROWS * DM / 8 / 256), blk, 0, stream>>>(x, xbf, MROWS * DM / 8);
    convT_bf16<<<dim3(DM / 32, NC_QKV / 32), blk, 0, stream>>>(Wqkv, wqkvt, DM, NC_QKV);
    convT_bf16<<<dim3(DM / 32, DM / 32), blk, 0, stream>>>(Wout, woutt, DM, DM);

    gemm_mfma<1><<<dim3(MROWS / 128, NC_QKV / 128), blk, 0, stream>>>(
        xbf, wqkvt, bqkv, (void*)qkv, DM, NC_QKV);

    attn_mfma<<<dim3(16, 32), blk, 0, stream>>>(qkv, ao);

    gemm_mfma<0><<<dim3(MROWS / 128, DM / 128), blk, 0, stream>>>(
        ao, woutt, bout, (void*)out, DM, DM);
}

// Round 11
// 209.155 us; speedup vs baseline: 1.2484x; 1.0130x over previous
//
#include <hip/hip_runtime.h>
#include <hip/hip_bf16.h>
#include <math.h>

// Problem constants
#define BB      4
#define NN      2048
#define DM      768
#define NH      8
#define DHH     96
#define BH      (BB*NH)          // 32
#define MROWS   (BB*NN)          // 8192
#define NC_QKV  (3*DM)           // 2304

typedef short v4s  __attribute__((ext_vector_type(4)));
typedef short v8s  __attribute__((ext_vector_type(8)));
typedef float v4f  __attribute__((ext_vector_type(4)));
typedef float v16f __attribute__((ext_vector_type(16)));
typedef unsigned int u32;

// log2(e)/sqrt(96) folded into Q at QKV-GEMM epilogue
#define SCQ 0.14724599350930152f

static __device__ __forceinline__ ushort f2bf(float f) {
    __hip_bfloat16 h = __float2bfloat16(f);
    return *reinterpret_cast<ushort*>(&h);
}

static __device__ __forceinline__ void gload_lds16(const ushort* g, ushort* l) {
    __builtin_amdgcn_global_load_lds(
        (const __attribute__((address_space(1))) void*)g,
        (__attribute__((address_space(3))) void*)l, 16, 0, 0);
}

// two 8B LDS loads 32B apart -> one v8s A-fragment (k-permutation pi)
static __device__ __forceinline__ v8s load2x4_o16(const ushort* p) {
    union { v4s h[2]; v8s s; } x;
    x.h[0] = *reinterpret_cast<const v4s*>(p);
    x.h[1] = *reinterpret_cast<const v4s*>(p + 16);
    return x.s;
}

static __device__ __forceinline__ v8s pack4(u32 a, u32 b, u32 c, u32 d) {
    union { u32 u[4]; v8s s; } x;
    x.u[0] = a; x.u[1] = b; x.u[2] = c; x.u[3] = d;
    return x.s;
}
static __device__ __forceinline__ u32 bfpair(float lo, float hi) {
    return (u32)f2bf(lo) | ((u32)f2bf(hi) << 16);
}

// ---------------------------------------------------------------------------
// fp32 -> bf16 elementwise (n8 = count/8)
// ---------------------------------------------------------------------------
__global__ __launch_bounds__(256)
void conv_bf16(const float* __restrict__ in, ushort* __restrict__ out, int n8)
{
    int i = blockIdx.x * 256 + threadIdx.x;
    if (i >= n8) return;
    const float4* p = reinterpret_cast<const float4*>(in) + (size_t)i * 2;
    float4 a = p[0], b = p[1];
    ushort r[8] = {f2bf(a.x), f2bf(a.y), f2bf(a.z), f2bf(a.w),
                   f2bf(b.x), f2bf(b.y), f2bf(b.z), f2bf(b.w)};
    *reinterpret_cast<v8s*>(out + (size_t)i * 8) = *reinterpret_cast<v8s*>(r);
}

// ---------------------------------------------------------------------------
// fp32 W[K][N] -> bf16 Wt[N][K] (tiled transpose)
// ---------------------------------------------------------------------------
__global__ __launch_bounds__(256)
void convT_bf16(const float* __restrict__ W, ushort* __restrict__ Wt, int K, int N)
{
    __shared__ ushort t[32][33];
    const int k0 = blockIdx.x * 32, n0 = blockIdx.y * 32;
    const int tx = threadIdx.x & 31, ty = threadIdx.x >> 5;
    #pragma unroll
    for (int r = ty; r < 32; r += 8)
        t[tx][r] = f2bf(W[(size_t)(k0 + r) * N + n0 + tx]);
    __syncthreads();
    #pragma unroll
    for (int r = ty; r < 32; r += 8)
        Wt[(size_t)(n0 + r) * K + k0 + tx] = t[r][tx];
}

// ---------------------------------------------------------------------------
// bf16 MFMA GEMM (round-6/7 form, harness-proven; vmcnt experiment reverted)
// ---------------------------------------------------------------------------
template<int SCATTER>
__global__ __launch_bounds__(256)
void gemm_mfma(const ushort* __restrict__ A, const ushort* __restrict__ Bt,
               const float* __restrict__ bias, void* __restrict__ outp,
               int K, int Ncols)
{
    __shared__ ushort As[2][8192];   // [buf][8 kslots][128 rows][8]
    __shared__ ushort Bs[2][8192];

    const int tid  = threadIdx.x;
    const int lane = tid & 63;
    const int wv   = tid >> 6;
    const int l31  = lane & 31;
    const int lhi  = lane >> 5;
    const int wr   = wv >> 1, wc = wv & 1;

    const int ny   = gridDim.y;
    const int id   = blockIdx.y * gridDim.x + blockIdx.x;
    const int c8   = id & 7;
    const int j    = id >> 3;
    const int hy   = (j >= (ny >> 1) * 8) ? 1 : 0;
    const int w    = j - hy * (ny >> 1) * 8;
    const int bx   = c8 * 8 + (w & 7);
    const int by   = hy * (ny >> 1) + (w >> 3);
    const int row0 = bx * 128;
    const int col0 = by * 128;

    v16f acc[2][2];
    #pragma unroll
    for (int mi = 0; mi < 2; ++mi)
        #pragma unroll
        for (int nj = 0; nj < 2; ++nj)
            #pragma unroll
            for (int i = 0; i < 16; ++i) acc[mi][nj][i] = 0.0f;

#define STAGE_G(bsel, kk) do {                                                  \
    _Pragma("unroll")                                                           \
    for (int c = 0; c < 4; ++c) {                                               \
        const int g   = c * 4 + wv;                                             \
        const int idx = g * 64 + lane;                                          \
        const int ss  = idx >> 7, rr = idx & 127;                               \
        gload_lds16(&A [(size_t)(row0 + rr) * K + (kk) + ss * 8],               \
                    &As[bsel][g * 512]);                                        \
        gload_lds16(&Bt[(size_t)(col0 + rr) * K + (kk) + ss * 8],               \
                    &Bs[bsel][g * 512]);                                        \
    }                                                                           \
} while (0)

    STAGE_G(0, 0);
    __syncthreads();

    const int nk = K >> 6;
    for (int t = 0; t < nk; ++t) {
        const int cur = t & 1;
        if (t + 1 < nk) STAGE_G(cur ^ 1, (t + 1) << 6);

        #pragma unroll
        for (int s16 = 0; s16 < 4; ++s16) {
            const int ks = s16 * 2 + lhi;
            v8s a0 = *reinterpret_cast<const v8s*>(&As[cur][(size_t)(ks * 128 + 64 * wr + l31) * 8]);
            v8s a1 = *reinterpret_cast<const v8s*>(&As[cur][(size_t)(ks * 128 + 64 * wr + 32 + l31) * 8]);
            v8s b0 = *reinterpret_cast<const v8s*>(&Bs[cur][(size_t)(ks * 128 + 64 * wc + l31) * 8]);
            v8s b1 = *reinterpret_cast<const v8s*>(&Bs[cur][(size_t)(ks * 128 + 64 * wc + 32 + l31) * 8]);
            acc[0][0] = __builtin_amdgcn_mfma_f32_32x32x16_bf16(a0, b0, acc[0][0], 0, 0, 0);
            acc[0][1] = __builtin_amdgcn_mfma_f32_32x32x16_bf16(a0, b1, acc[0][1], 0, 0, 0);
            acc[1][0] = __builtin_amdgcn_mfma_f32_32x32x16_bf16(a1, b0, acc[1][0], 0, 0, 0);
            acc[1][1] = __builtin_amdgcn_mfma_f32_32x32x16_bf16(a1, b1, acc[1][1], 0, 0, 0);
        }
        __syncthreads();
    }
#undef STAGE_G

    #pragma unroll
    for (int nj = 0; nj < 2; ++nj) {
        const int c = col0 + 64 * wc + 32 * nj + l31;
        const float bv = bias[c];
        #pragma unroll
        for (int mi = 0; mi < 2; ++mi) {
            #pragma unroll
            for (int r = 0; r < 16; ++r) {
                const int m = row0 + 64 * wr + 32 * mi + (r & 3) + 8 * (r >> 2) + 4 * lhi;
                float v = acc[mi][nj][r] + bv;
                if (SCATTER) {
                    const int s   = c / DM;
                    const int rem = c - s * DM;
                    const int h   = rem / DHH;
                    const int d   = rem - h * DHH;
                    const int b   = m >> 11;
                    const int n   = m & (NN - 1);
                    if (s == 0) v *= SCQ;
                    ((ushort*)outp)[((size_t)(s * BH + b * NH + h) * NN + n) * DHH + d] = f2bf(v);
                } else {
                    ((float*)outp)[(size_t)m * Ncols + c] = v;
                }
            }
        }
    }
}

// ---------------------------------------------------------------------------
// MFMA bf16 flash attention, 16x16x32 variant: 16 q-rows/wave -> 4096 waves
// total = 4 waves/SIMD (2x TLP vs the 32x32 structure's invariant 2048).
// Swapped QK^T: S^T = mfma16(K, Q); C layout col=lane&15(=q),
// row=(lane>>4)*4+j(=kv) [m89-verified]. Exchange-free P via shared
// k-permutation pi(g,i)=g*4+(i&3)+16*(i>>2) on PV's A (V^T, two 8B LDS
// reads at +0/+32B) and B (packed exp values). Single-buffered K/V LDS
// (25.5 KB -> 4 blocks/CU) with the r8-proven read->barrier->write->barrier
// handoff; next-tile global->reg loads issued before compute.
// ---------------------------------------------------------------------------
__global__ __launch_bounds__(256, 4)
void attn_mfma(const ushort* __restrict__ qkv, ushort* __restrict__ attnout)
{
    __shared__ ushort Ks[6144];        // [g=d/8:12][kv=64][8]
    __shared__ ushort Vt[96][68];      // [d][kv], pad 68 (2-way on reads)

    const int tid  = threadIdx.x;
    const int lane = tid & 63;
    const int wv   = tid >> 6;          // 0..3
    const int l15  = lane & 15;
    const int g4   = lane >> 4;         // 0..3

    // bh-clustered XCD swizzle (grid = (32 qt, 32 bh)): 4 bh per XCD
    const int id   = blockIdx.y * gridDim.x + blockIdx.x;
    const int c8   = id & 7;
    const int j    = id >> 3;            // 0..127
    const int bh   = c8 * 4 + (j & 3);
    const int qt   = j >> 2;             // 0..31
    const int q0   = qt * 64;
    const int b    = bh >> 3, h = bh & 7;

    const ushort* Qg = qkv + (size_t)bh * NN * DHH;
    const ushort* Kg = qkv + ((size_t)BH + bh) * NN * DHH;
    const ushort* Vg = qkv + ((size_t)2 * BH + bh) * NN * DHH;

    // Q B-fragments (pre-scaled by SCQ): col=q=l15, k=d=c*32+g4*8+i
    const int qrow = q0 + wv * 16 + l15;
    v8s qf[3];
    #pragma unroll
    for (int c = 0; c < 3; ++c)
        qf[c] = *reinterpret_cast<const v8s*>(&Qg[(size_t)qrow * DHH + c * 32 + g4 * 8]);

    v4f o[6];
    #pragma unroll
    for (int dt = 0; dt < 6; ++dt)
        #pragma unroll
        for (int i = 0; i < 4; ++i) o[dt][i] = 0.0f;
    float ds = 0.0f;

    // ---- prologue: reg-stage tile 0 -> LDS
    {
        const size_t rowb = (size_t)lane * DHH;
        v8s kr[3], vr[3];
        #pragma unroll
        for (int i = 0; i < 3; ++i) {
            kr[i] = *reinterpret_cast<const v8s*>(&Kg[rowb + (wv * 3 + i) * 8]);
            vr[i] = *reinterpret_cast<const v8s*>(&Vg[rowb + (i * 4 + wv) * 8]);
        }
        #pragma unroll
        for (int i = 0; i < 3; ++i) {
            *reinterpret_cast<v8s*>(&Ks[(wv * 3 + i) * 512 + lane * 8]) = kr[i];
            #pragma unroll
            for (int jj = 0; jj < 8; ++jj)
                Vt[(i * 4 + wv) * 8 + jj][lane] = (ushort)vr[i][jj];
        }
    }
    __syncthreads();

    for (int t = 0; t < 32; ++t) {
        // issue next-tile global->reg loads early (land under compute)
        v8s kr0, kr1, kr2, vr0, vr1, vr2;
        if (t < 31) {
            const size_t rowb = (size_t)((t + 1) * 64 + lane) * DHH;
            kr0 = *reinterpret_cast<const v8s*>(&Kg[rowb + (wv * 3 + 0) * 8]);
            kr1 = *reinterpret_cast<const v8s*>(&Kg[rowb + (wv * 3 + 1) * 8]);
            kr2 = *reinterpret_cast<const v8s*>(&Kg[rowb + (wv * 3 + 2) * 8]);
            vr0 = *reinterpret_cast<const v8s*>(&Vg[rowb + (0 * 4 + wv) * 8]);
            vr1 = *reinterpret_cast<const v8s*>(&Vg[rowb + (1 * 4 + wv) * 8]);
            vr2 = *reinterpret_cast<const v8s*>(&Vg[rowb + (2 * 4 + wv) * 8]);
        }

        // two 32-kv halves: QK (2 S-tiles) -> softmax -> PV (6 d-tiles)
        #pragma unroll
        for (int th = 0; th < 2; ++th) {
            v4f s0, s1;
            #pragma unroll
            for (int i = 0; i < 4; ++i) { s0[i] = 0.0f; s1[i] = 0.0f; }
            __builtin_amdgcn_s_setprio(1);
            #pragma unroll
            for (int c = 0; c < 3; ++c) {
                v8s kf0 = *reinterpret_cast<const v8s*>(
                    &Ks[((c * 4 + g4) * 64 + (th * 2 + 0) * 16 + l15) * 8]);
                v8s kf1 = *reinterpret_cast<const v8s*>(
                    &Ks[((c * 4 + g4) * 64 + (th * 2 + 1) * 16 + l15) * 8]);
                s0 = __builtin_amdgcn_mfma_f32_16x16x32_bf16(kf0, qf[c], s0, 0, 0, 0);
                s1 = __builtin_amdgcn_mfma_f32_16x16x32_bf16(kf1, qf[c], s1, 0, 0, 0);
            }
            __builtin_amdgcn_s_setprio(0);

            // exp + denom; lane holds kv = th*32 + {g4*4+j, 16+g4*4+j}, q=l15
            float e0[4], e1[4];
            #pragma unroll
            for (int r = 0; r < 4; ++r) {
                e0[r] = exp2f(s0[r]);
                e1[r] = exp2f(s1[r]);
                ds += e0[r] + e1[r];
            }
            // B-frag slots i: kv_local32 = g4*4 + (i&3) + 16*(i>>2)
            v8s pf = pack4(bfpair(e0[0], e0[1]), bfpair(e0[2], e0[3]),
                           bfpair(e1[0], e1[1]), bfpair(e1[2], e1[3]));

            // PV: A = V^T with the same k-permutation (8B reads at +0/+32B)
            __builtin_amdgcn_s_setprio(1);
            #pragma unroll
            for (int dt = 0; dt < 6; ++dt) {
                const ushort* vp = &Vt[dt * 16 + l15][th * 32 + g4 * 4];
                v8s va = load2x4_o16(vp);
                o[dt] = __builtin_amdgcn_mfma_f32_16x16x32_bf16(va, pf, o[dt], 0, 0, 0);
            }
            __builtin_amdgcn_s_setprio(0);
        }

        // single-buffer handoff: reads done -> write next tile -> visible
        if (t < 31) {
            __syncthreads();
            *reinterpret_cast<v8s*>(&Ks[(wv * 3 + 0) * 512 + lane * 8]) = kr0;
            *reinterpret_cast<v8s*>(&Ks[(wv * 3 + 1) * 512 + lane * 8]) = kr1;
            *reinterpret_cast<v8s*>(&Ks[(wv * 3 + 2) * 512 + lane * 8]) = kr2;
            #pragma unroll
            for (int jj = 0; jj < 8; ++jj) Vt[(0 * 4 + wv) * 8 + jj][lane] = (ushort)vr0[jj];
            #pragma unroll
            for (int jj = 0; jj < 8; ++jj) Vt[(1 * 4 + wv) * 8 + jj][lane] = (ushort)vr1[jj];
            #pragma unroll
            for (int jj = 0; jj < 8; ++jj) Vt[(2 * 4 + wv) * 8 + jj][lane] = (ushort)vr2[jj];
            __syncthreads();
        }
    }

    // denominator: combine the 4 lane-groups sharing q=l15
    ds += __shfl_xor(ds, 16, 64);
    ds += __shfl_xor(ds, 32, 64);
    const float inv = 1.0f / ds;

    // write O^T: lane q = l15 -> n; regs = d (4 consecutive per dt -> 8B)
    const int n = q0 + wv * 16 + l15;
    ushort* orow = attnout + ((size_t)(b * NN + n)) * DM + h * DHH;
    #pragma unroll
    for (int dt = 0; dt < 6; ++dt) {
        const int d0 = dt * 16 + g4 * 4;
        uint2 pk;
        pk.x = bfpair(o[dt][0] * inv, o[dt][1] * inv);
        pk.y = bfpair(o[dt][2] * inv, o[dt][3] * inv);
        *reinterpret_cast<uint2*>(&orow[d0]) = pk;
    }
}

// ---------------------------------------------------------------------------
extern "C" void kernel_launch(void* const* d_in, const int* in_sizes, int n_in,
                              void* d_out, int out_size, void* d_ws, size_t ws_size,
                              hipStream_t stream)
{
    (void)in_sizes; (void)n_in; (void)out_size; (void)ws_size;
    const float* x    = (const float*)d_in[0];
    const float* Wqkv = (const float*)d_in[1];
    const float* bqkv = (const float*)d_in[2];
    const float* Wout = (const float*)d_in[3];
    const float* bout = (const float*)d_in[4];
    float* out = (float*)d_out;

    ushort* qkv   = (ushort*)d_ws;                       // [3][BH][NN][96] bf16
    ushort* ao    = qkv   + (size_t)3 * BH * NN * DHH;   // [8192][768] bf16
    ushort* xbf   = ao    + (size_t)MROWS * DM;          // [8192][768] bf16
    ushort* wqkvt = xbf   + (size_t)MROWS * DM;          // [2304][768] bf16
    ushort* woutt = wqkvt + (size_t)DM * NC_QKV;         // [768][768]  bf16

    dim3 blk(256);

    conv_bf16<<<dim3(MROWS * DM / 8 / 256), blk, 0, stream>>>(x, xbf, MROWS * DM / 8);
    convT_bf16<<<dim3(DM / 32, NC_QKV / 32), blk, 0, stream>>>(Wqkv, wqkvt, DM, NC_QKV);
    convT_bf16<<<dim3(DM / 32, DM / 32), blk, 0, stream>>>(Wout, woutt, DM, DM);

    gemm_mfma<1><<<dim3(MROWS / 128, NC_QKV / 128), blk, 0, stream>>>(
        xbf, wqkvt, bqkv, (void*)qkv, DM, NC_QKV);

    attn_mfma<<<dim3(32, 32), blk, 0, stream>>>(qkv, ao);

    gemm_mfma<0><<<dim3(MROWS / 128, DM / 128), blk, 0, stream>>>(
        ao, woutt, bout, (void*)out, DM, DM);
}